// Round 1
// baseline (310.300 us; speedup 1.0000x reference)
//
#include <hip/hip_runtime.h>

#define TT 512
#define BIGS 1.4426950408889634e10f   // BIG(1e10) * log2(e), scaled domain
#define LOG2E 1.4426950408889634f
#define M2L  (-2.0f * 1.4426950408889634f)
#define LN2F 0.69314718055994531f
#define P_SS 16                       // ticks per superstep (barrier period)
#define G_LAG 80                      // band lag in ticks (>= P_SS + 63 + 1)
#define N_SS 51                       // band3 last tick 574 at s=50
#define RW   96                       // D-ring column window (mult of 16; lifetime needs > 92)
#define RSTR 98                       // ring row stride in words: (RSTR-1) odd -> tick-read banks
                                      // (t*98 + (U-t) mod 96) % 32 = (t+U)%32 -> 2-way (free)

typedef _Float16 h2 __attribute__((ext_vector_type(2)));

__device__ __forceinline__ unsigned pk(float a, float b) {
    h2 v; v.x = (_Float16)a; v.y = (_Float16)b;
    return __builtin_bit_cast(unsigned, v);
}

#if __has_builtin(__builtin_amdgcn_fdot2)
#define FDOT2(a, b, c) __builtin_amdgcn_fdot2(__builtin_bit_cast(h2, (a)), \
                                              __builtin_bit_cast(h2, (b)), (c), false)
#else
__device__ __forceinline__ float fdot2_sw(unsigned a, unsigned b, float c) {
    h2 ha = __builtin_bit_cast(h2, a), hb = __builtin_bit_cast(h2, b);
    return c + (float)ha.x * (float)hb.x + (float)ha.y * (float)hb.y;
}
#define FDOT2(a, b, c) fdot2_sw((a), (b), (c))
#endif

// permuted Z index, pure bitops (wraps any int j onto a valid row; garbage rows
// only feed inactive/masked ticks)
#define ZROW(jv) (((((jv) & 1)) << 8) | ((((jv) >> 1)) & 255))
// c mod 96 via magic-mul; exact for 0 <= c <= 32735
#define MOD96(c) ((c) - 96 * (((c) * 21846) >> 21))

// ---------------------------------------------------------------------------
// Round 11: distance production hoisted out of the tick.
//  * Per superstep, each band-wave batch-computes the 16 upcoming columns of
//    -  a(i,j) = <X_i, Z_j>  (16 FDOT2 per row-pair, independent chains, ZA
//    reads are wave-uniform -> broadcast, conflict-free) and stores the
//    f16-packed row-pair into a private LDS ring ring[wv][t][.] (96-col
//    window, stride 98 words -> tick reads are 2-way banked = free).
//  * Tick body shrinks to: seam reads + 1x b32 ring read + 1x b32 z^2 read
//    + softmin. The 2x ds_read_b128 Z refill, 16 FDOT2 and uint4 traffic
//    leave the serial tick path entirely.
//  * Schedule (4 bands, P_SS=16, G_LAG=80), seam rings, renorm, boundary
//    shfl surgery: identical to round 10 (verified).
//  Ring lifetime: col c last prefetched at tick c+61; slot reused by col
//  c+96 produced at superstep base >= c+65 (tile lead-1) -> safe.
// ---------------------------------------------------------------------------
__global__ __launch_bounds__(256, 1) void k_fused(const float* __restrict__ X,
                                                  const float* __restrict__ Z,
                                                  const float* __restrict__ w,
                                                  float* __restrict__ out) {
    const int tt = threadIdx.x;
    const int t  = tt & 63;          // lane
    const int wv = tt >> 6;          // wave = row band 0..3
    const int n  = blockIdx.x;       // sample

    __shared__ uint4 ZA[2][512];     // Z rows fp16-packed, permuted idx
    __shared__ float Zs2p[512];      // LOG2E*|z|^2 at permuted idx
    __shared__ float seamK[4][64];   // seam rings (K); band0 = const border
    __shared__ float seamS[4][64];   // seam rings (sm)
    __shared__ unsigned ring[4][64][RSTR];  // f16x2 xz-dot (row pair) per band

    // ---- stage Z into LDS: thread tt handles rows tt, tt+256 ----
#pragma unroll
    for (int h = 0; h < 2; ++h) {
        const int r = tt + h * 256;
        const float4* zp = (const float4*)(Z + (size_t)r * 16);
        const float4 a0 = zp[0], a1 = zp[1], a2 = zp[2], a3 = zp[3];
        float sv = 0.0f;
        sv = fmaf(a0.x, a0.x, sv); sv = fmaf(a0.y, a0.y, sv);
        sv = fmaf(a0.z, a0.z, sv); sv = fmaf(a0.w, a0.w, sv);
        sv = fmaf(a1.x, a1.x, sv); sv = fmaf(a1.y, a1.y, sv);
        sv = fmaf(a1.z, a1.z, sv); sv = fmaf(a1.w, a1.w, sv);
        sv = fmaf(a2.x, a2.x, sv); sv = fmaf(a2.y, a2.y, sv);
        sv = fmaf(a2.z, a2.z, sv); sv = fmaf(a2.w, a2.w, sv);
        sv = fmaf(a3.x, a3.x, sv); sv = fmaf(a3.y, a3.y, sv);
        sv = fmaf(a3.z, a3.z, sv); sv = fmaf(a3.w, a3.w, sv);
        const int idx = ((r & 1) << 8) | (r >> 1);
        ZA[0][idx] = make_uint4(pk(a0.x, a0.y), pk(a0.z, a0.w),
                                pk(a1.x, a1.y), pk(a1.z, a1.w));
        ZA[1][idx] = make_uint4(pk(a2.x, a2.y), pk(a2.z, a2.w),
                                pk(a3.x, a3.y), pk(a3.z, a3.w));
        Zs2p[idx] = LOG2E * sv;
    }
    // seam rings -> (BIGS, 1): matrix border; band 0 ring is never written
    (&seamK[0][0])[tt] = BIGS;
    (&seamS[0][0])[tt] = 1.0f;
    // zero the D-ring (unproduced slots read only by masked ticks; zero keeps
    // everything finite)
    {
        unsigned* rp = &ring[0][0][0];
        for (int q = tt; q < 4 * 64 * RSTR; q += 256) rp[q] = 0u;
    }

    // ---- X rows for this lane (rows i0, i0+1) -> registers ----
    const int i0 = 128 * wv + 2 * t;
    unsigned Xu[2][8];
    float    xs2[2];
    const float* xp = X + ((size_t)n * TT + i0) * 16;
#pragma unroll
    for (int q = 0; q < 2; ++q) {
        const float4* xr = (const float4*)(xp + q * 16);
        const float4 a0 = xr[0], a1 = xr[1], a2 = xr[2], a3 = xr[3];
        float sv = 0.0f;
        sv = fmaf(a0.x, a0.x, sv); sv = fmaf(a0.y, a0.y, sv);
        sv = fmaf(a0.z, a0.z, sv); sv = fmaf(a0.w, a0.w, sv);
        sv = fmaf(a1.x, a1.x, sv); sv = fmaf(a1.y, a1.y, sv);
        sv = fmaf(a1.z, a1.z, sv); sv = fmaf(a1.w, a1.w, sv);
        sv = fmaf(a2.x, a2.x, sv); sv = fmaf(a2.y, a2.y, sv);
        sv = fmaf(a2.z, a2.z, sv); sv = fmaf(a2.w, a2.w, sv);
        sv = fmaf(a3.x, a3.x, sv); sv = fmaf(a3.y, a3.y, sv);
        sv = fmaf(a3.z, a3.z, sv); sv = fmaf(a3.w, a3.w, sv);
        xs2[q] = LOG2E * sv;
        Xu[q][0] = pk(a0.x, a0.y); Xu[q][1] = pk(a0.z, a0.w);
        Xu[q][2] = pk(a1.x, a1.y); Xu[q][3] = pk(a1.z, a1.w);
        Xu[q][4] = pk(a2.x, a2.y); Xu[q][5] = pk(a2.z, a2.w);
        Xu[q][6] = pk(a3.x, a3.y); Xu[q][7] = pk(a3.z, a3.w);
    }
    const float wgt = w[n];
    const float* rK = &seamK[wv][0];
    const float* rS = &seamS[wv][0];
    unsigned* const rg = &ring[wv][t][0];
    __syncthreads();

    float RpK[2], RpS[2], poK, poS, smK, smS, bnK, bnS;
    unsigned rv[2];
    float zzv[2];
    RpK[0] = RpK[1] = BIGS; RpS[0] = RpS[1] = 1.0f;
    poK = BIGS; poS = 1.0f; smK = BIGS; smS = 1.0f;
    bnK = BIGS; bnS = 1.0f;
    rv[0] = rv[1] = 0u; zzv[0] = zzv[1] = 0.0f;

#define TICK(par, tl)                                                          \
    {                                                                          \
        const float unK = (t == 0) ? smK : bnK;                                \
        const float unS = (t == 0) ? smS : bnS;                                \
        smK = rK[((tl) + 1) & 63];           /* seam for next tick */          \
        smS = rS[((tl) + 1) & 63];                                             \
        const unsigned av = rv[par];                                           \
        const float zz = zzv[par];                                             \
        {   /* refill this slot for tick tl+2 (col (tl+2)-t) */                \
            const int cpf = (tl) + 2;                                          \
            int wq = MOD96(cpf) - t;                                           \
            wq += (wq < 0) ? 96 : 0;                                           \
            rv[par] = rg[wq];                                                  \
            zzv[par] = Zs2p[ZROW(cpf - t)];                                    \
        }                                                                      \
        const h2 ah = __builtin_bit_cast(h2, av);                              \
        const float dd0 = fmaf(M2L, (float)ah.x, xs2[0] + zz);                 \
        const float dd1 = fmaf(M2L, (float)ah.y, xs2[1] + zz);                 \
        /* (K,sm) softmin, unconditional (all operands finite) */              \
        const float l0K = RpK[0], l0S = RpS[0];                                \
        const float m0 = fminf(fminf(unK, l0K), poK);                          \
        const float s0 = exp2f(m0 - unK) * unS                                 \
                       + exp2f(m0 - l0K) * l0S                                 \
                       + exp2f(m0 - poK) * poS;                                \
        const float K0 = dd0 + m0;                                             \
        const float l1K = RpK[1], l1S = RpS[1];                                \
        const float m1 = fminf(fminf(K0, l1K), l0K);                           \
        const float s1 = exp2f(m1 - K0) * s0                                   \
                       + exp2f(m1 - l1K) * l1S                                 \
                       + exp2f(m1 - l0K) * l0S;                                \
        const float K1 = dd1 + m1;                                             \
        const int j = (tl) - t;                                                \
        const bool ok = (j >= 0) && (j < 512);                                 \
        RpK[0] = ok ? K0 : RpK[0];  RpS[0] = ok ? s0 : RpS[0];                 \
        RpK[1] = ok ? K1 : RpK[1];  RpS[1] = ok ? s1 : RpS[1];                 \
        if (ok && wv < 3 && t == 63) {                                         \
            seamK[wv + 1][j & 63] = RpK[1];                                    \
            seamS[wv + 1][j & 63] = RpS[1];                                    \
        }                                                                      \
        poK = unK; poS = unS;                                                  \
        bnK = __shfl_up(RpK[1], 1);          /* boundary for tick tl+1 */      \
        bnS = __shfl_up(RpS[1], 1);                                            \
    }

#define RENORM                                                                 \
    {                                                                          \
        _Pragma("unroll")                                                      \
        for (int q = 0; q < 2; ++q) {                                          \
            const int e = (int)(__float_as_uint(RpS[q]) >> 23) - 127;          \
            RpS[q] = __uint_as_float(__float_as_uint(RpS[q])                   \
                                     - ((unsigned)e << 23));                   \
            RpK[q] -= (float)e;                                                \
        }                                                                      \
    }

#pragma unroll 1
    for (int s = 0; s < N_SS; ++s) {
        const int tb = P_SS * s - G_LAG * wv;
        if (tb >= 0 && tb <= 574) {
            if (tb == 0) {
                // activation: DP state + boundary
                RpK[0] = RpK[1] = BIGS; RpS[0] = RpS[1] = 1.0f;
                poK = (wv == 0 && t == 0) ? 0.0f : BIGS; poS = 1.0f;  // corner
                bnK = BIGS; bnS = 1.0f;
                smK = rK[0]; smS = rS[0];
            }
            // ---- produce D-ring tile(s): cols [16*pt, 16*pt+15] ----
            // steady state: tile tb/16+1 (covers this superstep's prefetch
            // max col tb+17 and beyond); activation: tiles 0..1.
            {
                const int thi = (tb >> 4) + 1;
                int pt = (tb == 0) ? 0 : thi;
#pragma unroll 1
                for (; pt <= thi; ++pt) {
                    if (pt < 32) {
                        const int base = pt << 4;
                        const int wb = MOD96(base);   // {0,16,..,80}: no wrap
#pragma unroll
                        for (int cc = 0; cc < 16; ++cc) {
                            const int zr = ZROW(base + cc);   // wave-uniform
                            const uint4 z0 = ZA[0][zr], z1 = ZA[1][zr];
                            float a0 = 0.0f, a1 = 0.0f;
                            a0 = FDOT2(z0.x, Xu[0][0], a0);
                            a0 = FDOT2(z0.y, Xu[0][1], a0);
                            a0 = FDOT2(z0.z, Xu[0][2], a0);
                            a0 = FDOT2(z0.w, Xu[0][3], a0);
                            a0 = FDOT2(z1.x, Xu[0][4], a0);
                            a0 = FDOT2(z1.y, Xu[0][5], a0);
                            a0 = FDOT2(z1.z, Xu[0][6], a0);
                            a0 = FDOT2(z1.w, Xu[0][7], a0);
                            a1 = FDOT2(z0.x, Xu[1][0], a1);
                            a1 = FDOT2(z0.y, Xu[1][1], a1);
                            a1 = FDOT2(z0.z, Xu[1][2], a1);
                            a1 = FDOT2(z0.w, Xu[1][3], a1);
                            a1 = FDOT2(z1.x, Xu[1][4], a1);
                            a1 = FDOT2(z1.y, Xu[1][5], a1);
                            a1 = FDOT2(z1.z, Xu[1][6], a1);
                            a1 = FDOT2(z1.w, Xu[1][7], a1);
                            rg[wb + cc] = pk(a0, a1);
                        }
                    }
                }
            }
            if (tb == 0) {
                // prefetch slots for ticks 0,1 (cols 0-t, 1-t; t>0 lanes hit
                // unproduced/zero slots -> masked by ok)
                int w0 = 0 - t; w0 += (w0 < 0) ? 96 : 0;
                rv[0] = rg[w0]; zzv[0] = Zs2p[ZROW(0 - t)];
                int w1 = 1 - t; w1 += (w1 < 0) ? 96 : 0;
                rv[1] = rg[w1]; zzv[1] = Zs2p[ZROW(1 - t)];
            }
            TICK(0, tb + 0)  TICK(1, tb + 1)  TICK(0, tb + 2)  TICK(1, tb + 3)
            TICK(0, tb + 4)  TICK(1, tb + 5)  TICK(0, tb + 6)  TICK(1, tb + 7)
            RENORM
            TICK(0, tb + 8)  TICK(1, tb + 9)  TICK(0, tb + 10) TICK(1, tb + 11)
            TICK(0, tb + 12) TICK(1, tb + 13) TICK(0, tb + 14) TICK(1, tb + 15)
            RENORM
        }
        __syncthreads();
    }
#undef TICK
#undef RENORM

    // band 3, lane 63, row 511 at tick 574 -> R(511,511) = K - log2(sm)
    if (wv == 3 && t == 63) {
        atomicAdd(out, wgt * (RpK[1] - log2f(RpS[1])) * LN2F);
    }
}

__global__ void k_zero(float* out) {
    if (threadIdx.x == 0) out[0] = 0.0f;
}

extern "C" void kernel_launch(void* const* d_in, const int* in_sizes, int n_in,
                              void* d_out, int out_size, void* d_ws, size_t ws_size,
                              hipStream_t stream) {
    const float* X = (const float*)d_in[0];   // (64, 512, 16) f32
    const float* w = (const float*)d_in[1];   // (64,) f32
    const float* Z = (const float*)d_in[2];   // (512, 16) f32
    float* out = (float*)d_out;               // scalar f32

    hipLaunchKernelGGL(k_zero, dim3(1), dim3(64), 0, stream, out);
    hipLaunchKernelGGL(k_fused, dim3(64), dim3(256), 0, stream, X, Z, w, out);
}